// Round 5
// baseline (321.332 us; speedup 1.0000x reference)
//
#include <hip/hip_runtime.h>

// VQ-VAE quantizer — round 14: lane=code + 4-sample-batched channel-outer loop.
// Inputs fp32: z_e [32,64,64,64], codebook [512,64].
// Output fp32: z_q [8388608] ++ indices-as-float [131072].
//
// Reference (np, fp32): d = rn( rn(s1 + s2[k]) - 2*M32[k] ), argmin ties->lowest.
//   s1 = np.sum(z**2,axis=1):  square->round, pairwise-8 accumulators, no fma.
//   s2 = np.sum(cb**2,axis=1): same.
//   M32 = sgemm(z_flat, cb^T): sequential-c single-accumulator fmaf chain.
// The fp32 grid must be replicated EXACTLY (R8). All per-(n,k) chains below
// are bit-identical to R13 (passed, absmax 0) — only the schedule changes.
//
// R13 post-mortem: VGPR_Count=40 for the 4th kernel in a row => the unified-
// file allocator homes every long-lived 64-float array in AGPRs; VALU busy
// ran 2x the pure-fma model in R10..R13 => ~1 v_accvgpr_read per fma (VOP2
// v_fmac can't take AGPR in that slot). We can't force VGPR homing from
// source (R11 proved asm pins fail), so AMORTIZE: channel-outer, 4 samples
// per pass => each codebook element fetched once per 4 fmas (1.25 VALU/fma).
// 4 independent chains also give ILP to cover fma latency at 4 waves/SIMD.
// Pre-pass rewritten with fl4 loads (R13a used scalar loads; implied cost
// ~67us vs ~15us roofline).

typedef __attribute__((ext_vector_type(4))) float fl4;

// ---------- kernel A: z -> z_t[n][64] (row-contiguous) + s1[n] ----------
// 512 blocks x 256 threads; block = 256 samples of one image (256 | 4096).
__global__ __launch_bounds__(256)
void vq14a(const float* __restrict__ z, float* __restrict__ ow)
{
    __shared__ fl4   zl4[64][64];    // [c][s4]: 64KB, fl4 = 4 consecutive samples
    __shared__ float pl[8][256];     // np partial sums p[j] per sample: 8KB

    const int tid = threadIdx.x;
    const int n0  = blockIdx.x << 8;
    const int cq  = tid >> 6;        // 0..3  (wave id: whole wave = same cq)
    const int s4g = tid & 63;        // sample-group (4 samples)
    const size_t zb = (size_t)(n0 >> 12) * 262144 + (size_t)(n0 & 4095)
                    + ((size_t)s4g << 2);

    // Thread covers channels c = cq + 4j (j=0..15) for samples s4g*4..+3.
    // np s1: p[j] = sum_m z[m*8+j]^2 (square->round, add in m-ascending order).
    // This thread produces exactly p[cq] (j even) and p[cq+4] (j odd), both
    // m-ascending: c = cq,cq+8,..  and cq+4,cq+12,..  — np order preserved.
    float pq[4], pq4[4];
    #pragma unroll
    for (int j = 0; j < 16; ++j) {
        const int c = cq + (j << 2);
        const fl4 v = *(const fl4*)(z + zb + (size_t)c * 4096);  // 1KB/wave, coalesced
        zl4[c][s4g] = v;
        #pragma unroll
        for (int e = 0; e < 4; ++e) {
            const float sq = __fmul_rn(v[e], v[e]);   // np: z**2 rounds first
            if (j == 0)            pq[e]  = sq;                       // init p[cq]
            else if (j == 1)       pq4[e] = sq;                       // init p[cq+4]
            else if ((j & 1) == 0) pq[e]  = __fadd_rn(pq[e],  sq);    // m ascending
            else                   pq4[e] = __fadd_rn(pq4[e], sq);
        }
    }
    #pragma unroll
    for (int e = 0; e < 4; ++e) {
        pl[cq][(s4g << 2) + e]     = pq[e];
        pl[cq + 4][(s4g << 2) + e] = pq4[e];
    }
    __syncthreads();

    // s1[n] with the exact np pairwise tree: ((p0+p1)+(p2+p3))+((p4+p5)+(p6+p7))
    {
        const int s = tid;
        const float s1 = __fadd_rn(
            __fadd_rn(__fadd_rn(pl[0][s], pl[1][s]), __fadd_rn(pl[2][s], pl[3][s])),
            __fadd_rn(__fadd_rn(pl[4][s], pl[5][s]), __fadd_rn(pl[6][s], pl[7][s])));
        ow[8388608 + n0 + s] = s1;               // s1 -> indices region
    }

    // z_t rows: thread writes fl4 f=(it*256+tid) -> sample f>>4, channels (f&15)*4
    float* zt = ow + ((size_t)n0 << 6);
    #pragma unroll
    for (int it = 0; it < 16; ++it) {
        const int f  = (it << 8) + tid;
        const int nl = f >> 4;                   // local sample 0..255
        const int c0 = (f & 15) << 2;            // channel base
        fl4 v;
        #pragma unroll
        for (int e = 0; e < 4; ++e)
            v[e] = zl4[c0 + e][nl >> 2][nl & 3]; // 4-addr broadcast: conflict-free
        *(fl4*)(zt + ((size_t)f << 2)) = v;      // coalesced 16B stores
    }
}

// ---------- kernel B: lane=code, channel-outer 4-sample batches ----------
#define CBE(i) cbv[(i) >> 2][(i) & 3]

__global__ __launch_bounds__(512, 4)             // 4 waves/EU => <=128 unified regs
void vq14b(const float* __restrict__ cb,
           const float* __restrict__ zt,         // == ow (z_q region)
           const float* __restrict__ s1g,        // == ow + 8388608
           float* __restrict__ ow)
{
    __shared__ float s1l[128];
    __shared__ float cdl[8][128];                // per-wave candidate d
    __shared__ int   ckl[8][128];                // per-wave candidate k
    __shared__ int   ifin[128];

    const int tid  = threadIdx.x;
    const int w    = tid >> 6;                   // wave 0..7
    const int lane = tid & 63;
    const int n0   = blockIdx.x << 7;            // 1024 blocks x 128 samples
    const int k    = (w << 6) + lane;            // this lane's code

    // codebook row resident for the whole kernel (allocator will pick class)
    fl4 cbv[16];
    {
        const fl4* rp = (const fl4*)(cb + ((size_t)k << 6));
        #pragma unroll
        for (int j = 0; j < 16; ++j) cbv[j] = rp[j];
    }
    // s2 for this code: np order (square->round, pairwise-8, no fma)
    float s2k;
    {
        float q[8];
        #pragma unroll
        for (int j = 0; j < 8; ++j) q[j] = __fmul_rn(CBE(j), CBE(j));
        #pragma unroll
        for (int m = 1; m < 8; ++m)
            #pragma unroll
            for (int j = 0; j < 8; ++j) {
                const float v = CBE(m * 8 + j);
                q[j] = __fadd_rn(q[j], __fmul_rn(v, v));
            }
        s2k = __fadd_rn(__fadd_rn(__fadd_rn(q[0], q[1]), __fadd_rn(q[2], q[3])),
                        __fadd_rn(__fadd_rn(q[4], q[5]), __fadd_rn(q[6], q[7])));
    }

    if (tid < 128) s1l[tid] = s1g[n0 + tid];     // read BEFORE overwrite
    __syncthreads();

    // ---- sample loop: 4 samples/batch, channel-outer ----
    // Each a_i is a private c-ascending single-accumulator fmaf chain:
    // bit-identical to the reference per (n,k). CBE(c) fetched once per 4 fmas.
#define LOADC(B, C4) do {                                         \
        B##0 = *(const fl4*)(zr0 + ((C4) << 2));                  \
        B##1 = *(const fl4*)(zr1 + ((C4) << 2));                  \
        B##2 = *(const fl4*)(zr2 + ((C4) << 2));                  \
        B##3 = *(const fl4*)(zr3 + ((C4) << 2)); } while (0)
#define FMAC(B, C4) do {                                          \
        _Pragma("unroll")                                         \
        for (int e = 0; e < 4; ++e) {                             \
            const float cbe = CBE(((C4) << 2) + e);               \
            a0 = fmaf(B##0[e], cbe, a0);                          \
            a1 = fmaf(B##1[e], cbe, a1);                          \
            a2 = fmaf(B##2[e], cbe, a2);                          \
            a3 = fmaf(B##3[e], cbe, a3); } } while (0)
#define REDUCE(DI, SI) do {                                       \
        float dm = (DI);                                          \
        _Pragma("unroll")                                         \
        for (int off = 1; off < 64; off <<= 1)                    \
            dm = fminf(dm, __shfl_xor(dm, off, 64));              \
        const unsigned long long eq = __ballot((DI) == dm);       \
        if (lane == 0) {                                          \
            cdl[w][s0 + (SI)] = dm;                               \
            ckl[w][s0 + (SI)] = (w << 6) + (int)__ffsll((long long)eq) - 1; } } while (0)

    for (int sb = 0; sb < 32; ++sb) {
        const int s0 = sb << 2;
        const float* zr0 = zt + ((size_t)(n0 + s0) << 6);   // wave-uniform rows
        const float* zr1 = zr0 + 64;
        const float* zr2 = zr0 + 128;
        const float* zr3 = zr0 + 192;

        float a0 = 0.0f, a1 = 0.0f, a2 = 0.0f, a3 = 0.0f;
        fl4 x0, x1, x2, x3, y0, y1, y2, y3;
        LOADC(x, 0);
        LOADC(y, 1);  FMAC(x, 0);
        LOADC(x, 2);  FMAC(y, 1);
        LOADC(y, 3);  FMAC(x, 2);
        LOADC(x, 4);  FMAC(y, 3);
        LOADC(y, 5);  FMAC(x, 4);
        LOADC(x, 6);  FMAC(y, 5);
        LOADC(y, 7);  FMAC(x, 6);
        LOADC(x, 8);  FMAC(y, 7);
        LOADC(y, 9);  FMAC(x, 8);
        LOADC(x, 10); FMAC(y, 9);
        LOADC(y, 11); FMAC(x, 10);
        LOADC(x, 12); FMAC(y, 11);
        LOADC(y, 13); FMAC(x, 12);
        LOADC(x, 14); FMAC(y, 13);
        LOADC(y, 15); FMAC(x, 14);
                      FMAC(y, 15);

        // d = rn( rn(s1+s2) - 2*M ), 2*M exact
        const float d0 = __fsub_rn(__fadd_rn(s1l[s0 + 0], s2k), 2.0f * a0);
        const float d1 = __fsub_rn(__fadd_rn(s1l[s0 + 1], s2k), 2.0f * a1);
        const float d2 = __fsub_rn(__fadd_rn(s1l[s0 + 2], s2k), 2.0f * a2);
        const float d3 = __fsub_rn(__fadd_rn(s1l[s0 + 3], s2k), 2.0f * a3);

        REDUCE(d0, 0);
        REDUCE(d1, 1);
        REDUCE(d2, 2);
        REDUCE(d3, 3);
    }
    __syncthreads();                              // all zt/s1g reads complete

    // ---- cross-wave merge: ascending w, strict < => lowest k on ties ----
    if (tid < 128) {
        float bd = cdl[0][tid]; int bk = ckl[0][tid];
        #pragma unroll
        for (int ww = 1; ww < 8; ++ww) {
            const float dw = cdl[ww][tid];
            const int   kw = ckl[ww][tid];
            if (dw < bd) { bd = dw; bk = kw; }
        }
        ifin[tid] = bk;
        ow[8388608 + n0 + tid] = (float)bk;       // overwrite s1 slice (safe now)
    }
    __syncthreads();

    // ---- z_q gather: 128 samples x 64 floats, coalesced 16B stores ----
    float* ob = ow + ((size_t)n0 << 6);           // overwrite z_t slice (safe now)
    #pragma unroll
    for (int it = 0; it < 4; ++it) {
        const int o    = it * 2048 + (tid << 2);  // float offset [0, 8192)
        const int sloc = o >> 6;
        const int c0   = o & 63;
        const int idx  = ifin[sloc] & 511;
        const fl4 v = *(const fl4*)(cb + ((size_t)idx << 6) + c0);
        *(fl4*)(ob + o) = v;
    }
}

extern "C" void kernel_launch(void* const* d_in, const int* in_sizes, int n_in,
                              void* d_out, int out_size, void* d_ws, size_t ws_size,
                              hipStream_t stream) {
    const float* z  = (const float*)d_in[0];   // z_e fp32 [32,64,64,64]
    const float* cb = (const float*)d_in[1];   // codebook fp32 [512,64]
    float* out = (float*)d_out;                // fp32: z_q [8388608] ++ idx [131072]
    vq14a<<<512, 256, 0, stream>>>(z, out);
    vq14b<<<1024, 512, 0, stream>>>(cb, out, out + 8388608, out);
}

// Round 6
// 305.286 us; speedup vs baseline: 1.0526x; 1.0526x over previous
//
#include <hip/hip_runtime.h>

// VQ-VAE quantizer — round 15: inline-asm inner loop (s_load z + v_fmac SGPR×VGPR).
// Inputs fp32: z_e [32,64,64,64], codebook [512,64].
// Output fp32: z_q [8388608] ++ indices-as-float [131072].
//
// Reference (np, fp32): d = rn( rn(s1 + s2[k]) - 2*M32[k] ), argmin ties->lowest.
//   s1 = np.sum(z**2,axis=1):  square->round, pairwise-8 accumulators, no fma.
//   s2 = np.sum(cb**2,axis=1): same.
//   M32 = sgemm(z_flat, cb^T): sequential-c single-accumulator fmaf chain.
// The fp32 grid must be replicated EXACTLY (R8). v_fmac_f32 IS IEEE fma with
// D += S0*S1 — the asm chain below is bit-identical to R13's fmaf chain
// (R13 passed, absmax 0). Reduce / merge / gather copied verbatim from R13.
//
// R9-R14 post-mortem: five C++ restructurings all landed at 197-255us with
// VALU busy ~2.3x the pure-fma model. The compiler always inserts ~1 extra
// VALU op per fma for whichever long-lived 64-float array exists (unified-
// file AGPR homing / operand copies); source-level hints (launch_bounds,
// asm pins, LDS, batching) never removed it. R15 removes the compiler's
// choice: the inner loop is emitted as explicit asm —
//   4x s_load_dwordx16 (z row -> 64 SGPRs, wave-uniform, waitcnt INSIDE the
//   same asm block per guide rule #18), then 64x
//   v_fmac_f32 %acc, s_z[c], v_cb[c]   (VOP2: 1 SGPR operand legal; "v"
//   constraint forces cb into an arch VGPR at every use).
// 128 issue-cyc/sample/wave, zero slop. SMEM latency covered by TLP.

typedef __attribute__((ext_vector_type(4)))  float fl4;
typedef __attribute__((ext_vector_type(16))) int   si16;

// ---------- kernel A: z -> z_t[n][64] (row-contiguous) + s1[n] ----------
// (verbatim R13a — proven bits; R14a had a 16-way LDS read conflict)
__global__ __launch_bounds__(256)
void vq15a(const float* __restrict__ z, float* __restrict__ ow)
{
    __shared__ float zl[256][65];              // +1 dword pad: conflict-free
    const int tid = threadIdx.x;
    const int n0  = blockIdx.x << 8;           // 512 blocks x 256 samples
    const int n   = n0 + tid;
    const size_t base = (size_t)(n >> 12) * 262144 + (size_t)(n & 4095);

    float p[8];
    #pragma unroll
    for (int c = 0; c < 64; ++c) {
        const float v = z[base + (size_t)c * 4096];   // coalesced across tid
        zl[tid][c] = v;
        const float sq = __fmul_rn(v, v);             // np: z**2 rounds first
        if (c < 8) p[c] = sq;                         // m = 0
        else       p[c & 7] = __fadd_rn(p[c & 7], sq);
    }
    const float s1 = __fadd_rn(__fadd_rn(__fadd_rn(p[0],p[1]),__fadd_rn(p[2],p[3])),
                               __fadd_rn(__fadd_rn(p[4],p[5]),__fadd_rn(p[6],p[7])));
    ow[8388608 + n] = s1;                             // s1 -> indices region
    __syncthreads();

    // coalesced tile write: fl4 f = j*256+tid -> sample f>>4, chans (f&15)*4
    float* zt = ow + (size_t)n0 * 64;
    #pragma unroll
    for (int j = 0; j < 16; ++j) {
        const int f  = j * 256 + tid;
        const int nl = f >> 4, c0 = (f & 15) << 2;
        fl4 v;
        #pragma unroll
        for (int e = 0; e < 4; ++e) v[e] = zl[nl][c0 + e];  // <=4-way: cheap
        *(fl4*)(zt + ((size_t)f << 2)) = v;
    }
}

// ---------- kernel B: lane=code, asm inner loop ----------
#define CBE(i) cbv[(i) >> 2][(i) & 3]

__global__ __launch_bounds__(512, 2)          // 256-reg budget: no pressure excuse
void vq15b(const float* __restrict__ cb,
           const float* __restrict__ zt,      // == ow (z_q region)
           const float* __restrict__ s1g,     // == ow + 8388608
           float* __restrict__ ow)
{
    __shared__ float s1l[128];
    __shared__ float cdl[8][128];             // per-wave candidate d
    __shared__ int   ckl[8][128];             // per-wave candidate k
    __shared__ int   ifin[128];

    const int tid  = threadIdx.x;
    const int w    = tid >> 6;                // wave 0..7
    const int lane = tid & 63;
    const int n0   = blockIdx.x << 7;         // 1024 blocks x 128 samples
    const int k    = (w << 6) + lane;         // this lane's code

    // codebook row resident for the whole kernel
    fl4 cbv[16];
    {
        const fl4* rp = (const fl4*)(cb + ((size_t)k << 6));
        #pragma unroll
        for (int j = 0; j < 16; ++j) cbv[j] = rp[j];
    }
    // s2 for this code: np order (square->round, pairwise-8, no fma)
    float s2k;
    {
        float q[8];
        #pragma unroll
        for (int j = 0; j < 8; ++j) q[j] = __fmul_rn(CBE(j), CBE(j));
        #pragma unroll
        for (int m = 1; m < 8; ++m)
            #pragma unroll
            for (int j = 0; j < 8; ++j) {
                const float v = CBE(m * 8 + j);
                q[j] = __fadd_rn(q[j], __fmul_rn(v, v));
            }
        s2k = __fadd_rn(__fadd_rn(__fadd_rn(q[0],q[1]),__fadd_rn(q[2],q[3])),
                        __fadd_rn(__fadd_rn(q[4],q[5]),__fadd_rn(q[6],q[7])));
    }

    if (tid < 128) s1l[tid] = s1g[n0 + tid];  // read BEFORE overwrite
    __syncthreads();

    // ---- sample loop ----
    for (int s = 0; s < 128; ++s) {
        const float* zr = zt + ((size_t)(n0 + s) << 6);   // uniform -> "s" pair

        // z row -> 64 SGPRs. waitcnt INSIDE the block (guide rule #18: a
        // separate waitcnt asm can be hoisted past by reg-only consumers).
        si16 z0, z1, z2, z3;
        asm volatile(
            "s_load_dwordx16 %0, %4, 0x0\n\t"
            "s_load_dwordx16 %1, %4, 0x40\n\t"
            "s_load_dwordx16 %2, %4, 0x80\n\t"
            "s_load_dwordx16 %3, %4, 0xC0\n\t"
            "s_waitcnt lgkmcnt(0)"
            : "=s"(z0), "=s"(z1), "=s"(z2), "=s"(z3)
            : "s"(zr)
            : "memory");

        // 64-step single-accumulator chain, c ascending: exact ref grid.
        // v_fmac_f32 D,S0,S1 : D = rn(S0*S1 + D) — IEEE fma == fmaf.
        float acc = 0.0f;
        #pragma unroll
        for (int e = 0; e < 16; ++e)
            asm("v_fmac_f32 %0, %1, %2" : "+v"(acc) : "s"(z0[e]), "v"(CBE(e)));
        #pragma unroll
        for (int e = 0; e < 16; ++e)
            asm("v_fmac_f32 %0, %1, %2" : "+v"(acc) : "s"(z1[e]), "v"(CBE(16 + e)));
        #pragma unroll
        for (int e = 0; e < 16; ++e)
            asm("v_fmac_f32 %0, %1, %2" : "+v"(acc) : "s"(z2[e]), "v"(CBE(32 + e)));
        #pragma unroll
        for (int e = 0; e < 16; ++e)
            asm("v_fmac_f32 %0, %1, %2" : "+v"(acc) : "s"(z3[e]), "v"(CBE(48 + e)));

        const float T = __fadd_rn(s1l[s], s2k);           // np: rn(s1+s2)
        const float d = __fsub_rn(T, 2.0f * acc);         // np: rn(T-2M), 2M exact

        // wave argmin: value-min butterfly, then lowest lane among equals
        float dm = d;
        #pragma unroll
        for (int off = 1; off < 64; off <<= 1)
            dm = fminf(dm, __shfl_xor(dm, off, 64));
        const unsigned long long eq = __ballot(d == dm);
        if (lane == 0) {
            cdl[w][s] = dm;
            ckl[w][s] = (w << 6) + (int)__ffsll((long long)eq) - 1; // lowest k
        }
    }
    __syncthreads();                           // all zt/s1g reads complete

    // ---- cross-wave merge: ascending w, strict < => lowest k on ties ----
    if (tid < 128) {
        float bd = cdl[0][tid]; int bk = ckl[0][tid];
        #pragma unroll
        for (int ww = 1; ww < 8; ++ww) {
            const float dw = cdl[ww][tid];
            const int   kw = ckl[ww][tid];
            if (dw < bd) { bd = dw; bk = kw; }
        }
        ifin[tid] = bk;
        ow[8388608 + n0 + tid] = (float)bk;    // overwrite s1 slice (safe now)
    }
    __syncthreads();

    // ---- z_q gather: 128 samples x 64 floats, coalesced 16B stores ----
    float* ob = ow + ((size_t)n0 << 6);        // overwrite z_t slice (safe now)
    #pragma unroll
    for (int it = 0; it < 4; ++it) {
        const int o    = it * 2048 + (tid << 2);   // float offset [0, 8192)
        const int sloc = o >> 6;
        const int c0   = o & 63;
        const int idx  = ifin[sloc] & 511;
        const fl4 v = *(const fl4*)(cb + ((size_t)idx << 6) + c0);
        *(fl4*)(ob + o) = v;
    }
}

extern "C" void kernel_launch(void* const* d_in, const int* in_sizes, int n_in,
                              void* d_out, int out_size, void* d_ws, size_t ws_size,
                              hipStream_t stream) {
    const float* z  = (const float*)d_in[0];   // z_e fp32 [32,64,64,64]
    const float* cb = (const float*)d_in[1];   // codebook fp32 [512,64]
    float* out = (float*)d_out;                // fp32: z_q [8388608] ++ idx [131072]
    vq15a<<<512, 256, 0, stream>>>(z, out);
    vq15b<<<1024, 512, 0, stream>>>(cb, out, out + 8388608, out);
}